// Round 7
// baseline (156.950 us; speedup 1.0000x reference)
//
#include <hip/hip_runtime.h>

// CRF loss: sum_b(forward_score[b] - gold_score[b]).  B=512, T=1024, L=32.
//
// R7: fused chunked matrix-product scan with 2-way chain ILP per wave.
// - One block per batch: 512 thr = 8 waves; wave w owns chunks 2w, 2w+1
//   (NC=16 chunks of CL=64). The two chains are interleaved in one
//   instruction stream so each chain's MFMA-latency window is filled by the
//   other chain's VALU work (R6 showed 4 in-phase waves/SIMD leave VALU idle
//   50% of cycles; more waves are impossible at this reg/LDS footprint).
// - M_c = prod(D_t E) via 2 chained mfma_32x32x16_bf16 per step per chain.
// - Zero per-step cross-lane fixup: B fed from acc regs directly; E columns
//   statically permuted by the same bijection sigma (verified R6).
// - Renorm every 4 steps, exact 2^-e (proxy exponent of M[2][0]); last
//   measured e un-applied.
// - Gold (trans + emission) gathered in the preamble.
// - M_c -> LDS f32 (stride 33); wave 0 runs the 16-chunk matvec combine.
// Grid 512 x 512thr = 2 blocks/CU, 4 waves/SIMD, no workspace.

typedef float  f32x16 __attribute__((ext_vector_type(16)));
typedef short  s16x8  __attribute__((ext_vector_type(8)));

#define TT 1024
#define LL 32
#define BB 512
#define NC 16
#define CL 64
#define MS 33

union Frag { s16x8 v; unsigned u[4]; };

// pack two f32 -> u32 holding 2 bf16 (truncation): lo in [15:0], hi in [31:16]
__device__ __forceinline__ unsigned pack_bf16(float lo, float hi) {
    return __builtin_amdgcn_perm(__float_as_uint(hi), __float_as_uint(lo), 0x07060302u);
}

__global__ __launch_bounds__(512, 4) void crf_fused_kernel(
    const float* __restrict__ emission,    // [B, T, L]
    const int*   __restrict__ label_ids,   // [B, T]
    const float* __restrict__ transitions, // [L, L]
    float*       __restrict__ out)         // [1], pre-zeroed
{
    __shared__ __align__(16) float shM[NC][32 * MS];   // 67,584 B
    __shared__ float shQ[2][64];
    __shared__ float tgArr[8];             // gold partial per wave
    __shared__ int   capArr[NC];

    const int tid  = threadIdx.x;
    const int w    = tid >> 6;             // wave id; owns chunks 2w, 2w+1
    const int lane = tid & 63;
    const int j    = lane & 31;            // A row m / C-D col n
    const int h    = lane >> 5;            // k-half
    const int b    = blockIdx.x;
    const int t0   = w * (2 * CL);         // first timestep of chunk pair

    const int*   labB = label_ids + b * TT + t0;
    const float* emB  = emission + ((size_t)b * TT + t0) * LL + j;

    // ---- gold score partial (transitions + emission gather), preamble ----
    {
        float g = 0.0f;
#pragma unroll
        for (int u = 0; u < 2; ++u) {
            int tt = t0 + 64 * u + lane;
            int l1 = labB[64 * u + lane];
            int l0 = (tt == 0) ? 0 : label_ids[b * TT + tt - 1];   // SOS at -1
            g += transitions[(l1 << 5) + l0];
            g += emission[((size_t)b * TT + tt) * LL + l1];
            if (tt == TT - 1) g += transitions[32 + l1];           // trans[END,last]
        }
#pragma unroll
        for (int m = 32; m >= 1; m >>= 1) g += __shfl_xor(g, m, 64);
        if (lane == 0) tgArr[w] = g;
    }

    // ---- E with sigma-permuted columns: E0'[i] = E[j][(i&3)+8(i>>2)+4h] ----
    const float* trow = transitions + j * 32;
    float E0[8], E1[8];
#pragma unroll
    for (int i = 0; i < 8; ++i) {
        int col = (i & 3) + 8 * (i >> 2) + 4 * h;
        E0[i] = __expf(trow[col]);
        E1[i] = __expf(trow[16 + col]);
    }

    // ---- per-chain state ----
    Frag B0[2], B1[2];
#pragma unroll
    for (int i = 0; i < 8; ++i) {
        int row = (i & 3) + 8 * (i >> 2) + 4 * h;
        short id0 = (short)((row == j)      ? 0x3F80 : 0);   // bf16 1.0
        short id1 = (short)((row + 16 == j) ? 0x3F80 : 0);
        B0[0].v[i] = id0; B1[0].v[i] = id1;
        B0[1].v[i] = id0; B1[1].v[i] = id1;
    }

    f32x16 zc, acc[2];
#pragma unroll
    for (int i = 0; i < 16; ++i) zc[i] = 0.0f;

    float ring[2][8];
#pragma unroll
    for (int s = 0; s < 8; ++s) {
        ring[0][s] = emB[s * LL];
        ring[1][s] = emB[(CL + s) * LL];
    }

    float sc[2] = {1.0f, 1.0f};
    int   Cap[2] = {0, 0}, elast[2] = {0, 0};

    for (int s0 = 0; s0 < CL; s0 += 8) {
#pragma unroll
        for (int k = 0; k < 8; ++k) {
            const int s = s0 + k;
            const int nf = (s + 8 < CL) ? (s + 8) : (CL - 1);   // ring refill idx
#pragma unroll
            for (int q = 0; q < 2; ++q) {
                float feat = ring[q][k];
                float fs = ((k & 3) == 0) ? (__expf(feat) * sc[q]) : __expf(feat);

                Frag A0, A1;
#pragma unroll
                for (int p = 0; p < 4; ++p) {
                    A0.u[p] = pack_bf16(fs * E0[2 * p], fs * E0[2 * p + 1]);
                    A1.u[p] = pack_bf16(fs * E1[2 * p], fs * E1[2 * p + 1]);
                }

                acc[q] = __builtin_amdgcn_mfma_f32_32x32x16_bf16(A0.v, B0[q].v, zc, 0, 0, 0);
                acc[q] = __builtin_amdgcn_mfma_f32_32x32x16_bf16(A1.v, B1[q].v, acc[q], 0, 0, 0);

                if ((k & 3) == 3) {        // group-end renorm (proxy M[2][0])
                    int pb = __builtin_amdgcn_readlane(__float_as_int(acc[q][2]), 0);
                    int e  = ((pb >> 23) & 0xff) - 127;
                    sc[q] = __int_as_float((127 - e) << 23);     // exact 2^-e
                    Cap[q] += e;
                    elast[q] = e;
                }

                ring[q][k] = emB[(q * CL + nf) * LL];

                // next B operand: direct reg feed (sigma layout), pack only
#pragma unroll
                for (int p = 0; p < 4; ++p) {
                    B0[q].u[p] = pack_bf16(acc[q][2 * p],     acc[q][2 * p + 1]);
                    B1[q].u[p] = pack_bf16(acc[q][8 + 2 * p], acc[q][9 + 2 * p]);
                }
            }
        }
    }

    // ---- store both chunk matrices to LDS (f32, padded stride) ----
#pragma unroll
    for (int q = 0; q < 2; ++q) {
        Cap[q] -= elast[q];                // final measured e never applied
#pragma unroll
        for (int r = 0; r < 16; ++r) {
            int row = (r & 3) + 8 * (r >> 2) + 4 * h;
            shM[2 * w + q][row * MS + j] = acc[q][r];
        }
        if (lane == 0) capArr[2 * w + q] = Cap[q];
    }

    __syncthreads();

    // ---- wave 0: sequential 16-chunk matvec combine ----
    if (w == 0) {
        const float Eend = __expf(transitions[32 + j]);   // exp(trans[END][j])
        float q = (j == 0) ? 1.0f : 0.0f;                 // one-hot SOS
        int   Cq = 0;

#pragma unroll
        for (int c = 0; c < NC; ++c) {
            shQ[c & 1][lane] = q;
            asm volatile("s_waitcnt lgkmcnt(0)" ::: "memory");
            __builtin_amdgcn_wave_barrier();
            const float* Mrow = &shM[c][j * MS];
            const float* qv   = &shQ[c & 1][h * 32];
            float a0 = 0.f, a1 = 0.f, a2 = 0.f, a3 = 0.f;
#pragma unroll
            for (int i = 0; i < 32; i += 4) {
                a0 = fmaf(Mrow[i],     qv[i],     a0);
                a1 = fmaf(Mrow[i + 1], qv[i + 1], a1);
                a2 = fmaf(Mrow[i + 2], qv[i + 2], a2);
                a3 = fmaf(Mrow[i + 3], qv[i + 3], a3);
            }
            float qn = (a0 + a1) + (a2 + a3);
            int pb = __builtin_amdgcn_readlane(__float_as_int(qn), 2);
            int e  = ((pb >> 23) & 0xff) - 127;
            qn *= __int_as_float((127 - e) << 23);        // exact 2^-e
            Cq += e + capArr[c];
            q = qn;
        }

        float v = q * Eend;
#pragma unroll
        for (int m = 16; m >= 1; m >>= 1) v += __shfl_xor(v, m, 32);
        float fwd = __logf(v) + (float)Cq * 0.69314718055994531f;

        float gold = 0.0f;
#pragma unroll
        for (int c = 0; c < 8; ++c) gold += tgArr[c];

        if (lane == 0) atomicAdd(out, fwd - gold);
    }
}

extern "C" void kernel_launch(void* const* d_in, const int* in_sizes, int n_in,
                              void* d_out, int out_size, void* d_ws, size_t ws_size,
                              hipStream_t stream)
{
    const float* emission    = (const float*)d_in[0];
    const int*   label_ids   = (const int*)d_in[1];
    const float* transitions = (const float*)d_in[2];
    float* out = (float*)d_out;

    hipMemsetAsync(out, 0, sizeof(float), stream);
    crf_fused_kernel<<<BB, 512, 0, stream>>>(emission, label_ids, transitions, out);
}

// Round 9
// 136.212 us; speedup vs baseline: 1.1522x; 1.1522x over previous
//
#include <hip/hip_runtime.h>

// CRF loss: sum_b(forward_score[b] - gold_score[b]).  B=512, T=1024, L=32.
//
// R8b = R6 structure (proven exact, 64 us kernel) + VALU diet + wave skew.
// - One block per batch: 512 thr = 8 waves = 8 chunks of 128 steps; each wave
//   computes M_c = prod(D_t E) via 2 chained mfma_32x32x16_bf16 per step.
// - B fed from acc regs directly; E columns statically permuted by the same
//   bijection sigma (no per-step cross-lane fixup) [verified R6].
// - Diet: fs*E via f32x2 ext-vector -> v_pk_mul_f32 (8 instead of 16 muls);
//   loop tail-split so the last 8 steps have no refill and the main body's
//   refill uses unclamped immediate offsets.
// - Skew: one-time s_sleep (constant-operand switch; s_sleep imm = 64*N cyc)
//   staggers the 4 waves/SIMD so their MFMA-stall windows interleave instead
//   of phase-locking (R6: 50% idle).
// - Renorm every 4 steps, exact 2^-e via proxy exponent of M[2][0]; last
//   measured e un-applied. Gold (trans+emit) gathered in preamble.
// - M_c -> LDS f32 (stride 33); wave 0 runs the 8-chunk matvec combine.
// Grid 512 x 512thr = 2 blocks/CU, 4 waves/SIMD, no workspace.

typedef float  f32x16 __attribute__((ext_vector_type(16)));
typedef short  s16x8  __attribute__((ext_vector_type(8)));
typedef float  f32x2  __attribute__((ext_vector_type(2)));

#define TT 1024
#define LL 32
#define BB 512
#define NC 8
#define CL 128
#define MS 33

union Frag { s16x8 v; unsigned u[4]; };

// pack two f32 -> u32 holding 2 bf16 (truncation): lo in [15:0], hi in [31:16]
__device__ __forceinline__ unsigned pack_bf16(float lo, float hi) {
    return __builtin_amdgcn_perm(__float_as_uint(hi), __float_as_uint(lo), 0x07060302u);
}

__device__ __forceinline__ void skew_sleep(int n) {
    switch (n & 3) {
        case 1: __builtin_amdgcn_s_sleep(1); break;
        case 2: __builtin_amdgcn_s_sleep(2); break;
        case 3: __builtin_amdgcn_s_sleep(3); break;
        default: break;
    }
}

__global__ __launch_bounds__(NC * 64, 4) void crf_fused_kernel(
    const float* __restrict__ emission,    // [B, T, L]
    const int*   __restrict__ label_ids,   // [B, T]
    const float* __restrict__ transitions, // [L, L]
    float*       __restrict__ out)         // [1], pre-zeroed
{
    __shared__ __align__(16) float shM[NC][32 * MS];   // 33,792 B
    __shared__ float shQ[2][64];
    __shared__ float tgArr[NC];
    __shared__ int   capArr[NC];

    const int tid  = threadIdx.x;
    const int w    = tid >> 6;             // wave id = chunk id
    const int lane = tid & 63;
    const int j    = lane & 31;            // A row m / C-D col n
    const int h    = lane >> 5;            // k-half
    const int b    = blockIdx.x;
    const int t0   = w * CL;

    const int*   labB = label_ids + b * TT + t0;
    const float* emB  = emission + ((size_t)b * TT + t0) * LL + j;

    // ---- gold score partial (transitions + emission gather), preamble ----
    {
        float g = 0.0f;
#pragma unroll
        for (int u = 0; u < 2; ++u) {
            int tt = t0 + 64 * u + lane;
            int l1 = labB[64 * u + lane];
            int l0 = (tt == 0) ? 0 : label_ids[b * TT + tt - 1];   // SOS at -1
            g += transitions[(l1 << 5) + l0];
            g += emission[((size_t)b * TT + tt) * LL + l1];
            if (tt == TT - 1) g += transitions[32 + l1];           // trans[END,last]
        }
#pragma unroll
        for (int m = 32; m >= 1; m >>= 1) g += __shfl_xor(g, m, 64);
        if (lane == 0) tgArr[w] = g;
    }

    // ---- E, sigma-permuted cols, as f32x2 pairs for v_pk_mul_f32 ----
    const float* trow = transitions + j * 32;
    f32x2 E0v[4], E1v[4];
#pragma unroll
    for (int p = 0; p < 4; ++p) {
        int c0 = ((2 * p) & 3)     + 8 * ((2 * p) >> 2)     + 4 * h;
        int c1 = ((2 * p + 1) & 3) + 8 * ((2 * p + 1) >> 2) + 4 * h;
        E0v[p][0] = __expf(trow[c0]);      E0v[p][1] = __expf(trow[c1]);
        E1v[p][0] = __expf(trow[16 + c0]); E1v[p][1] = __expf(trow[16 + c1]);
    }

    // ---- B = identity in sigma layout (bf16 1.0 = 0x3F80) ----
    Frag B0, B1;
#pragma unroll
    for (int i = 0; i < 8; ++i) {
        int row = (i & 3) + 8 * (i >> 2) + 4 * h;
        B0.v[i] = (short)((row == j)      ? 0x3F80 : 0);
        B1.v[i] = (short)((row + 16 == j) ? 0x3F80 : 0);
    }

    f32x16 zc, acc;
#pragma unroll
    for (int i = 0; i < 16; ++i) zc[i] = 0.0f;

    float ring[8];
#pragma unroll
    for (int s = 0; s < 8; ++s) ring[s] = emB[s * LL];

    float sc = 1.0f;
    int   Cap = 0, elast = 0;

    // ---- de-phase the 4 waves/SIMD (one-time, s_sleep = 64*N cyc) ----
    skew_sleep(w + ((blockIdx.x & 1) << 1));

    // one recurrence step; refill only when told (tail has none)
    auto step = [&](int k, int s, bool refill) {
        float feat = ring[k];
        float fs = ((k & 3) == 0) ? (__expf(feat) * sc) : __expf(feat);
        f32x2 fs2; fs2[0] = fs; fs2[1] = fs;

        Frag A0, A1;
#pragma unroll
        for (int p = 0; p < 4; ++p) {
            f32x2 a = fs2 * E0v[p];
            f32x2 c = fs2 * E1v[p];
            A0.u[p] = pack_bf16(a[0], a[1]);
            A1.u[p] = pack_bf16(c[0], c[1]);
        }

        acc = __builtin_amdgcn_mfma_f32_32x32x16_bf16(A0.v, B0.v, zc, 0, 0, 0);
        acc = __builtin_amdgcn_mfma_f32_32x32x16_bf16(A1.v, B1.v, acc, 0, 0, 0);

        if ((k & 3) == 3) {                // group-end renorm (proxy M[2][0])
            int pb = __builtin_amdgcn_readlane(__float_as_int(acc[2]), 0);
            int e  = ((pb >> 23) & 0xff) - 127;
            sc = __int_as_float((127 - e) << 23);   // exact 2^-e
            Cap += e;
            elast = e;
        }

        if (refill) ring[k] = emB[(s + 8) * LL];

        // next B operand: direct reg feed (sigma layout), pack only
#pragma unroll
        for (int p = 0; p < 4; ++p) {
            B0.u[p] = pack_bf16(acc[2 * p],     acc[2 * p + 1]);
            B1.u[p] = pack_bf16(acc[8 + 2 * p], acc[9 + 2 * p]);
        }
    };

    for (int s0 = 0; s0 < CL - 8; s0 += 8) {
#pragma unroll
        for (int k = 0; k < 8; ++k) step(k, s0 + k, true);
    }
#pragma unroll
    for (int k = 0; k < 8; ++k) step(k, CL - 8 + k, false);

    Cap -= elast;                          // final measured e never applied

    // ---- store M_c to LDS (f32, padded stride -> conflict-free) ----
#pragma unroll
    for (int r = 0; r < 16; ++r) {
        int row = (r & 3) + 8 * (r >> 2) + 4 * h;
        shM[w][row * MS + j] = acc[r];
    }
    if (lane == 0) capArr[w] = Cap;

    __syncthreads();

    // ---- wave 0: sequential 8-chunk matvec combine ----
    if (w == 0) {
        const float Eend = __expf(transitions[32 + j]);   // exp(trans[END][j])
        float q = (j == 0) ? 1.0f : 0.0f;                 // one-hot SOS
        int   Cq = 0;
        float gold = 0.0f;

#pragma unroll
        for (int c = 0; c < NC; ++c) {
            shQ[c & 1][lane] = q;
            asm volatile("s_waitcnt lgkmcnt(0)" ::: "memory");
            __builtin_amdgcn_wave_barrier();
            const float* Mrow = &shM[c][j * MS];
            const float* qv   = &shQ[c & 1][h * 32];
            float a0 = 0.f, a1 = 0.f, a2 = 0.f, a3 = 0.f;
#pragma unroll
            for (int i = 0; i < 32; i += 4) {
                a0 = fmaf(Mrow[i],     qv[i],     a0);
                a1 = fmaf(Mrow[i + 1], qv[i + 1], a1);
                a2 = fmaf(Mrow[i + 2], qv[i + 2], a2);
                a3 = fmaf(Mrow[i + 3], qv[i + 3], a3);
            }
            float qn = (a0 + a1) + (a2 + a3);
            int pb = __builtin_amdgcn_readlane(__float_as_int(qn), 2);
            int e  = ((pb >> 23) & 0xff) - 127;
            qn *= __int_as_float((127 - e) << 23);        // exact 2^-e
            Cq += e + capArr[c];
            gold += tgArr[c];
            q = qn;
        }

        float v = q * Eend;
#pragma unroll
        for (int m = 16; m >= 1; m >>= 1) v += __shfl_xor(v, m, 32);
        float fwd = __logf(v) + (float)Cq * 0.69314718055994531f;

        if (lane == 0) atomicAdd(out, fwd - gold);
    }
}

extern "C" void kernel_launch(void* const* d_in, const int* in_sizes, int n_in,
                              void* d_out, int out_size, void* d_ws, size_t ws_size,
                              hipStream_t stream)
{
    const float* emission    = (const float*)d_in[0];
    const int*   label_ids   = (const int*)d_in[1];
    const float* transitions = (const float*)d_in[2];
    float* out = (float*)d_out;

    (void)hipMemsetAsync(out, 0, sizeof(float), stream);
    crf_fused_kernel<<<BB, NC * 64, 0, stream>>>(emission, label_ids, transitions, out);
}